// Round 4
// baseline (717.849 us; speedup 1.0000x reference)
//
#include <hip/hip_runtime.h>
#include <stdint.h>

// AnyprecisionLinear: out[s,o] = sum_k x[s,k] * lut[o, code(o,k)>>4]
// M=2048, N=8192, K=8192. fp32 in/out, bf16 MFMA compute.
//
// R4 changes vs R3:
//  - gemm_bt: A (x-strip, 2 MB, L2-hot: shared by 64 blocks) is now loaded
//    per-lane DIRECTLY from global into MFMA fragments -- no sA, no A-side
//    ds_reads, and the barrier drain only covers B staging (4 global_load_lds
//    per wave instead of 8). LDS drops 32->16 KB.
//  - n-major block swizzle: consecutive block ids share the same B n-strip
//    (16 m-blocks each) so B-tile fetches hit L2 instead of HBM.
//  - dequant/cvt unchanged (R3's ~55 us is near the 45 us memory floor;
//    the residual pre-gemm gap is fixed harness reset traffic).

#define M_DIM 2048
#define N_DIM 8192
#define K_DIM 8192
#define BM 128
#define BN 128
#define BK 64

typedef __bf16 bf16x8 __attribute__((ext_vector_type(8)));
typedef float f32x16 __attribute__((ext_vector_type(16)));

__device__ __forceinline__ unsigned int f2bf(float f) {
  // round-to-nearest-even fp32 -> bf16
  unsigned int u = __float_as_uint(f);
  return (u + 0x7FFFu + ((u >> 16) & 1u)) >> 16;
}

// ---------------- dequant: qweight (int32-packed 8-bit codes) -> bf16 W ----
// One wave per output row; per-lane replicated LUT (entry stride 256 B, lane
// stride 4 B -> bank = lane%32, data-independent, conflict-free gathers).
__global__ __launch_bounds__(256) void dequant_kernel(
    const int4* __restrict__ qw4,
    const float* __restrict__ lut,
    unsigned short* __restrict__ wb) {
  __shared__ unsigned int slut[4 * 16 * 64];  // 16 KB
  const int wave = threadIdx.x >> 6;
  const int lane = threadIdx.x & 63;
  const int row = (blockIdx.x << 2) + wave;

  unsigned int* tbl = slut + wave * (16 * 64) + lane;
  const float* lr = lut + row * 16;
#pragma unroll
  for (int e = 0; e < 16; ++e) tbl[e * 64] = f2bf(lr[e]);

  const int4* src = qw4 + (size_t)row * 512 + lane;
  unsigned short* dst = wb + (size_t)row * K_DIM + lane * 16;

#pragma unroll
  for (int it = 0; it < 8; ++it) {
    int4 q = src[it * 64];
    unsigned int w[4] = {(unsigned int)q.x, (unsigned int)q.y,
                         (unsigned int)q.z, (unsigned int)q.w};
    unsigned int v[16];
#pragma unroll
    for (int j = 0; j < 4; ++j) {
#pragma unroll
      for (int k = 0; k < 4; ++k)
        v[j * 4 + k] = tbl[((w[j] >> (8 * k + 4)) & 15u) * 64];
    }
    uint4 o0, o1;
    o0.x = v[0] | (v[1] << 16);   o0.y = v[2]  | (v[3] << 16);
    o0.z = v[4] | (v[5] << 16);   o0.w = v[6]  | (v[7] << 16);
    o1.x = v[8] | (v[9] << 16);   o1.y = v[10] | (v[11] << 16);
    o1.z = v[12] | (v[13] << 16); o1.w = v[14] | (v[15] << 16);
    uint4* dp = (uint4*)(dst + it * 1024);
    dp[0] = o0;
    dp[1] = o1;
  }
}

// ---------------- x fp32 -> bf16, 8 elements/thread, 16 B stores -----------
__global__ __launch_bounds__(256) void cvt_x_kernel(
    const float4* __restrict__ x4, unsigned int* __restrict__ xb) {
  const int idx = blockIdx.x * 256 + threadIdx.x;
  float4 a = x4[2 * idx];
  float4 b = x4[2 * idx + 1];
  uint4 o;
  o.x = f2bf(a.x) | (f2bf(a.y) << 16);
  o.y = f2bf(a.z) | (f2bf(a.w) << 16);
  o.z = f2bf(b.x) | (f2bf(b.y) << 16);
  o.w = f2bf(b.z) | (f2bf(b.w) << 16);
  ((uint4*)xb)[idx] = o;
}

// ---------------- GEMM: C = A * B^T, 32x32x16 bf16 MFMA -------------------
// A: M x K bf16 row-major (direct global fragment loads, L2-hot),
// B: N x K bf16 row-major (XOR-swizzled LDS via global_load_lds width 16),
// C: M x N fp32. Block 256 thr (4 waves), tile 128x128, BK=64, 16 KB LDS.
// Wave tile 64x64 = 2x2 of 32x32.
// A/B operand layout: row/col = lane&31, k = (lane>>5)*8 + j.
// C/D: col = lane&31, row = (reg&3) + 8*(reg>>2) + 4*(lane>>5)  [m74/m101].
__global__ __launch_bounds__(256) void gemm_bt(
    const unsigned short* __restrict__ A,
    const unsigned short* __restrict__ B,
    float* __restrict__ C) {
  __shared__ __align__(16) unsigned short sB[BN * BK];  // 16 KB

  const int tid = threadIdx.x;
  const int wave = tid >> 6;
  const int lane = tid & 63;

  // n-major swizzle: 16 consecutive blocks share one n-strip (same B tiles).
  const int bid = blockIdx.x;
  const int m0 = (bid & 15) * BM;
  const int n0 = (bid >> 4) * BN;

  const int wm = (wave & 1) * 64;
  const int wn = (wave >> 1) * 64;

  // B staging source coords (swizzled column): LDS chunk c of row r holds
  // global k-chunk c ^ (r&7).
  const int srow = lane >> 3;
  const int scol = ((lane & 7) ^ (lane >> 3)) * 8;

  const int laneN = lane & 31;   // operand m/n index
  const int half = lane >> 5;    // k-half (0: k 0-7, 1: k 8-15)
  const int sw = laneN & 7;      // reader XOR key (== row&7)

  // A fragment base: row m0+wm+laneN, k offset half*8 (+t*32 rows, +k0+kk)
  const unsigned short* Abase =
      A + (size_t)(m0 + wm + laneN) * K_DIM + half * 8;

  f32x16 acc[2][2];
#pragma unroll
  for (int i = 0; i < 2; ++i)
#pragma unroll
    for (int j = 0; j < 2; ++j)
#pragma unroll
      for (int r = 0; r < 16; ++r) acc[i][j][r] = 0.0f;

  for (int k0 = 0; k0 < K_DIM; k0 += BK) {
    // stage B tile: 16 chunks of 1 KB, wave w owns chunks w*4..w*4+3
#pragma unroll
    for (int r = 0; r < 4; ++r) {
      const int chunk = wave * 4 + r;
      const int row = chunk * 8 + srow;
      const unsigned short* gb = B + (size_t)(n0 + row) * K_DIM + k0 + scol;
      __builtin_amdgcn_global_load_lds(
          (const __attribute__((address_space(1))) void*)gb,
          (__attribute__((address_space(3))) void*)(sB + chunk * 512),
          16, 0, 0);
    }
    __syncthreads();

#pragma unroll
    for (int kk = 0; kk < BK; kk += 16) {
      const int c = ((kk >> 3) + half) ^ sw;  // swizzled LDS chunk
      bf16x8 af[2], bfr[2];
#pragma unroll
      for (int t = 0; t < 2; ++t) {
        af[t]  = *(const bf16x8*)(Abase + (size_t)t * 32 * K_DIM + k0 + kk);
        bfr[t] = *(const bf16x8*)(sB + (wn + t * 32 + laneN) * BK + c * 8);
      }
#pragma unroll
      for (int i = 0; i < 2; ++i)
#pragma unroll
        for (int j = 0; j < 2; ++j)
          acc[i][j] = __builtin_amdgcn_mfma_f32_32x32x16_bf16(
              af[i], bfr[j], acc[i][j], 0, 0, 0);
    }
    __syncthreads();
  }

  // epilogue: C/D layout col=lane&31, row=(reg&3)+8*(reg>>2)+4*half
#pragma unroll
  for (int i = 0; i < 2; ++i)
#pragma unroll
    for (int j = 0; j < 2; ++j) {
      const int rbase = m0 + wm + i * 32 + 4 * half;
      const int col = n0 + wn + j * 32 + laneN;
#pragma unroll
      for (int r = 0; r < 16; ++r) {
        const int rrow = rbase + (r & 3) + 8 * (r >> 2);
        C[(size_t)rrow * N_DIM + col] = acc[i][j][r];
      }
    }
}

// Safety-net fallback (only if ws_size < 160 MB): correct fp32, slow.
__global__ void naive_kernel(const float* __restrict__ x,
                             const int* __restrict__ qw,
                             const float* __restrict__ lut,
                             float* __restrict__ out) {
  int o = blockIdx.x * blockDim.x + threadIdx.x;
  int s = blockIdx.y;
  const float* xr = x + (size_t)s * K_DIM;
  const unsigned int* qr = (const unsigned int*)qw + (size_t)o * (K_DIM / 4);
  const float* l = lut + o * 16;
  float acc = 0.f;
  for (int w = 0; w < K_DIM / 4; ++w) {
    unsigned int q = qr[w];
    acc += xr[w * 4 + 0] * l[(q >> 4) & 15u]
         + xr[w * 4 + 1] * l[(q >> 12) & 15u]
         + xr[w * 4 + 2] * l[(q >> 20) & 15u]
         + xr[w * 4 + 3] * l[(q >> 28) & 15u];
  }
  out[(size_t)s * N_DIM + o] = acc;
}

extern "C" void kernel_launch(void* const* d_in, const int* in_sizes, int n_in,
                              void* d_out, int out_size, void* d_ws, size_t ws_size,
                              hipStream_t stream) {
  const float* x   = (const float*)d_in[0];
  const int*   qw  = (const int*)d_in[1];
  const float* lut = (const float*)d_in[2];
  float* out = (float*)d_out;

  const size_t wb_elems = (size_t)N_DIM * K_DIM;   // 128 MB bf16
  const size_t xb_elems = (size_t)M_DIM * K_DIM;   //  32 MB bf16
  const size_t need = (wb_elems + xb_elems) * sizeof(unsigned short);

  if (ws_size >= need) {
    unsigned short* wb = (unsigned short*)d_ws;
    unsigned short* xb = wb + wb_elems;

    hipLaunchKernelGGL(dequant_kernel, dim3(N_DIM / 4), dim3(256), 0, stream,
                       (const int4*)qw, lut, wb);

    const int n_thr = M_DIM * K_DIM / 8;           // 8 elem/thread
    hipLaunchKernelGGL(cvt_x_kernel, dim3(n_thr / 256), dim3(256), 0, stream,
                       (const float4*)x, (unsigned int*)xb);

    hipLaunchKernelGGL(gemm_bt, dim3((N_DIM / BN) * (M_DIM / BM)), dim3(256),
                       0, stream, xb, wb, out);
  } else {
    dim3 grid(N_DIM / 256, M_DIM);
    hipLaunchKernelGGL(naive_kernel, grid, dim3(256), 0, stream, x, qw, lut, out);
  }
}